// Round 17
// baseline (1024.133 us; speedup 1.0000x reference)
//
#include <hip/hip_runtime.h>

// KNNGraph bruteforce-blas, euclidean, k=16, include self.
// x: (N=4, M=8192, D=64) fp32. Output: int32 src[N*M*K] then dst[N*M*K].
//
// VALIDATED reference model (R9, absmax=0 — numerics FROZEN):
//   x2  = np.sum(x*x,-1): squares rounded per-element, FLOAT_pairwise_sum
//         n=64 NPY_SIMD path: 4 vec accs (vstep=4), serial blocks,
//         combine (r0+r1)+(r2+r3), double-hadd (S0+S1)+(S2+S3).
//   dot = np.einsum baseline-SSE: per-16 block REVERSED muladd chain
//         v_l = p0l+(p1l+(p2l+(p3l+v_l))), double-hadd (v0+v1)+(v2+v3).
//   d2  = fl(fl(x2j+x2c) - fl(2*dot)); stable ties by lower index.
//
// R17: occupancy fix. R16 partial was latency-stalled at 2 waves/SIMD
// (Q=2 halves the grid; select cost scales per-row so Q=2 saved little).
// Now: Q=1, direct-global uniform candidate reads, P=8 -> 4096 waves
// (4/SIMD), amdgpu_waves_per_eu(4) caps VGPR at 128. Select stays
// packed-u32 bubble (R14). Rescore stays 4x-parallel (R16).

#define MM 8192
#define NN 4
#define DD 64
#define KK 16
#define TK 20            // stage-A keep per chunk (16 + 4 safety margin)
#define NROWS (NN * MM)  // 32768

typedef float f32x2 __attribute__((ext_vector_type(2)));

// numpy SIMD pairwise sum of squares (SSE baseline), n=64. FROZEN.
__global__ __launch_bounds__(256) void norms_np_kernel(
    const float* __restrict__ x, float* __restrict__ x2) {
#pragma clang fp contract(off)
  int r = blockIdx.x * 256 + threadIdx.x;
  if (r >= NROWS) return;
  const float4* p = (const float4*)(x + (size_t)r * DD);
  float s[DD];
#pragma unroll
  for (int i = 0; i < DD / 4; ++i) {
    float4 v = p[i];
    s[4 * i + 0] = v.x * v.x;
    s[4 * i + 1] = v.y * v.y;
    s[4 * i + 2] = v.z * v.z;
    s[4 * i + 3] = v.w * v.w;
  }
  float acc[4][4];
#pragma unroll
  for (int c = 0; c < 4; ++c)
#pragma unroll
    for (int l = 0; l < 4; ++l) acc[c][l] = s[4 * c + l];
#pragma unroll
  for (int b = 1; b < 4; ++b)
#pragma unroll
    for (int c = 0; c < 4; ++c)
#pragma unroll
      for (int l = 0; l < 4; ++l)
        acc[c][l] = acc[c][l] + s[16 * b + 4 * c + l];
  float S[4];
#pragma unroll
  for (int l = 0; l < 4; ++l)
    S[l] = (acc[0][l] + acc[1][l]) + (acc[2][l] + acc[3][l]);
  x2[r] = (S[0] + S[1]) + (S[2] + S[3]);
}

// Packed compare-swap: sA=min, sB=max (u32 => (quantized key, idx) lex).
#define PSTEP(sA, sB)                       \
  do {                                      \
    unsigned lo_ = min((sA), (sB));         \
    unsigned hi_ = max((sA), (sB));         \
    (sA) = lo_; (sB) = hi_;                 \
  } while (0)

#define PBUBBLE20(S)                                              \
  do {                                                            \
    PSTEP(S##18, S##19); PSTEP(S##17, S##18); PSTEP(S##16, S##17);\
    PSTEP(S##15, S##16); PSTEP(S##14, S##15); PSTEP(S##13, S##14);\
    PSTEP(S##12, S##13); PSTEP(S##11, S##12); PSTEP(S##10, S##11);\
    PSTEP(S##9,  S##10); PSTEP(S##8,  S##9);  PSTEP(S##7,  S##8); \
    PSTEP(S##6,  S##7);  PSTEP(S##5,  S##6);  PSTEP(S##4,  S##5); \
    PSTEP(S##3,  S##4);  PSTEP(S##2,  S##3);  PSTEP(S##1,  S##2); \
    PSTEP(S##0,  S##1);                                           \
  } while (0)

#define PDECL20(S)                                                          \
  unsigned S##0 = 0xFFFFFFFFu, S##1 = 0xFFFFFFFFu, S##2 = 0xFFFFFFFFu,      \
           S##3 = 0xFFFFFFFFu, S##4 = 0xFFFFFFFFu, S##5 = 0xFFFFFFFFu,      \
           S##6 = 0xFFFFFFFFu, S##7 = 0xFFFFFFFFu, S##8 = 0xFFFFFFFFu,      \
           S##9 = 0xFFFFFFFFu, S##10 = 0xFFFFFFFFu, S##11 = 0xFFFFFFFFu,    \
           S##12 = 0xFFFFFFFFu, S##13 = 0xFFFFFFFFu, S##14 = 0xFFFFFFFFu,   \
           S##15 = 0xFFFFFFFFu, S##16 = 0xFFFFFFFFu, S##17 = 0xFFFFFFFFu,   \
           S##18 = 0xFFFFFFFFu, S##19 = 0xFFFFFFFFu;

#define PSTORE20(BASE, S, C0)                                               \
  do {                                                                      \
    pi[(BASE) + 0]  = (int)(S##0  & IMASK) + (C0);                          \
    pi[(BASE) + 1]  = (int)(S##1  & IMASK) + (C0);                          \
    pi[(BASE) + 2]  = (int)(S##2  & IMASK) + (C0);                          \
    pi[(BASE) + 3]  = (int)(S##3  & IMASK) + (C0);                          \
    pi[(BASE) + 4]  = (int)(S##4  & IMASK) + (C0);                          \
    pi[(BASE) + 5]  = (int)(S##5  & IMASK) + (C0);                          \
    pi[(BASE) + 6]  = (int)(S##6  & IMASK) + (C0);                          \
    pi[(BASE) + 7]  = (int)(S##7  & IMASK) + (C0);                          \
    pi[(BASE) + 8]  = (int)(S##8  & IMASK) + (C0);                          \
    pi[(BASE) + 9]  = (int)(S##9  & IMASK) + (C0);                          \
    pi[(BASE) + 10] = (int)(S##10 & IMASK) + (C0);                          \
    pi[(BASE) + 11] = (int)(S##11 & IMASK) + (C0);                          \
    pi[(BASE) + 12] = (int)(S##12 & IMASK) + (C0);                          \
    pi[(BASE) + 13] = (int)(S##13 & IMASK) + (C0);                          \
    pi[(BASE) + 14] = (int)(S##14 & IMASK) + (C0);                          \
    pi[(BASE) + 15] = (int)(S##15 & IMASK) + (C0);                          \
    pi[(BASE) + 16] = (int)(S##16 & IMASK) + (C0);                          \
    pi[(BASE) + 17] = (int)(S##17 & IMASK) + (C0);                          \
    pi[(BASE) + 18] = (int)(S##18 & IMASK) + (C0);                          \
    pi[(BASE) + 19] = (int)(S##19 & IMASK) + (C0);                          \
  } while (0)

// packed-fp32 dual-fma on one candidate float4 (v_pk_fma_f32 x2)
#define PK2(QF4, WLO, WHI, ACC0, ACC1)                             \
  do {                                                             \
    f32x2 qlo_ = {(QF4).x, (QF4).y};                               \
    f32x2 qhi_ = {(QF4).z, (QF4).w};                               \
    ACC0 = __builtin_elementwise_fma(qlo_, (WLO), ACC0);           \
    ACC1 = __builtin_elementwise_fma(qhi_, (WHI), ACC1);           \
  } while (0)

// Q=1 partial, direct-global uniform candidate reads (no LDS, no barriers).
// P=8 -> 1024 blocks = 4096 waves = 4/SIMD for latency hiding.
template <int P>
__global__ __launch_bounds__(256)
__attribute__((amdgpu_waves_per_eu(4)))
void knn_partial_q1_kernel(
    const float* __restrict__ x, const float* __restrict__ x2,
    int* __restrict__ pi) {
  constexpr int IB = (P == 16) ? 9 : (P == 8) ? 10 : (P == 4) ? 11
                    : (P == 2) ? 12 : 13;
  constexpr unsigned IMASK = (1u << IB) - 1u;
  constexpr unsigned QMASK = ~IMASK;

  const int tid   = threadIdx.x;
  const int rb    = blockIdx.x / P;
  const int chunk = blockIdx.x % P;
  const int b     = rb >> 5;            // 32 row-blocks per batch
  const int row   = rb * 256 + tid;
  const int j     = row - b * MM;

  const float* __restrict__ xb  = x + (size_t)b * MM * DD;
  const float* __restrict__ x2b = x2 + b * MM;

  const float4* qp = (const float4*)(xb + (size_t)j * DD);
  float4 q0 = qp[0],  q1 = qp[1],  q2 = qp[2],  q3 = qp[3];
  float4 q4 = qp[4],  q5 = qp[5],  q6 = qp[6],  q7 = qp[7];
  float4 q8 = qp[8],  q9 = qp[9],  q10 = qp[10], q11 = qp[11];
  float4 q12 = qp[12], q13 = qp[13], q14 = qp[14], q15 = qp[15];

  PDECL20(s)

  const int C  = MM / P;
  const int c0 = chunk * C;

#pragma unroll 1
  for (int c = c0; c < c0 + C; ++c) {
    const float4* cp = (const float4*)(xb + (size_t)c * DD);  // uniform addr
    float x2c = x2b[c];
    f32x2 a0 = {0.f, 0.f}, a1 = {0.f, 0.f};
    {
      float4 w;
      f32x2 wlo, whi;
#define LOADW(I)  w = cp[I]; wlo = (f32x2){w.x, w.y}; whi = (f32x2){w.z, w.w}
      LOADW(0);  PK2(q0,  wlo, whi, a0, a1);
      LOADW(1);  PK2(q1,  wlo, whi, a0, a1);
      LOADW(2);  PK2(q2,  wlo, whi, a0, a1);
      LOADW(3);  PK2(q3,  wlo, whi, a0, a1);
      LOADW(4);  PK2(q4,  wlo, whi, a0, a1);
      LOADW(5);  PK2(q5,  wlo, whi, a0, a1);
      LOADW(6);  PK2(q6,  wlo, whi, a0, a1);
      LOADW(7);  PK2(q7,  wlo, whi, a0, a1);
      LOADW(8);  PK2(q8,  wlo, whi, a0, a1);
      LOADW(9);  PK2(q9,  wlo, whi, a0, a1);
      LOADW(10); PK2(q10, wlo, whi, a0, a1);
      LOADW(11); PK2(q11, wlo, whi, a0, a1);
      LOADW(12); PK2(q12, wlo, whi, a0, a1);
      LOADW(13); PK2(q13, wlo, whi, a0, a1);
      LOADW(14); PK2(q14, wlo, whi, a0, a1);
      LOADW(15); PK2(q15, wlo, whi, a0, a1);
#undef LOADW
    }
    f32x2 rr = a0 + a1;
    float dot = rr.x + rr.y;
    float key = fmaf(-2.f, dot, x2c);

    int ki = __float_as_int(key);
    unsigned mono = (unsigned)ki ^ ((unsigned)(ki >> 31) | 0x80000000u);
    unsigned pk = (mono & QMASK) | (unsigned)(c - c0);
    s19 = min(s19, pk);
    PBUBBLE20(s);
  }

  size_t base = ((size_t)row * P + chunk) * TK;
  PSTORE20(base, s, c0);
}

// FROZEN-numerics einsum block: per-product rounding then reversed adds.
#define EBLK(QA, QB, QC, QD, W0, W1, W2, W3)                                  \
  do {                                                                        \
    v0 = (QA).x * (W0).x +                                                    \
         ((QB).x * (W1).x + ((QC).x * (W2).x + ((QD).x * (W3).x + v0)));      \
    v1 = (QA).y * (W0).y +                                                    \
         ((QB).y * (W1).y + ((QC).y * (W2).y + ((QD).y * (W3).y + v1)));      \
    v2 = (QA).z * (W0).z +                                                    \
         ((QB).z * (W1).z + ((QC).z * (W2).z + ((QD).z * (W3).z + v2)));      \
    v3 = (QA).w * (W0).w +                                                    \
         ((QB).w * (W1).w + ((QC).w * (W2).w + ((QD).w * (W3).w + v3)));      \
  } while (0)

// Lexicographic (d2, idx) compare-swap (strict: stable).
#define LBSTEP(dA, iA, dB, iB)                                     \
  do {                                                             \
    bool s_ = ((dB) < (dA)) || ((dB) == (dA) && (iB) < (iA));      \
    float tl_ = s_ ? (dB) : (dA);                                  \
    float th_ = s_ ? (dA) : (dB);                                  \
    int   jl_ = s_ ? (iB) : (iA);                                  \
    int   jh_ = s_ ? (iA) : (iB);                                  \
    (dA) = tl_; (dB) = th_; (iA) = jl_; (iB) = jh_;                \
  } while (0)

// 4x-parallel rescore: 4 threads/row, exact frozen key, local lex top-16,
// 4-way sorted merge via LDS (bit-identical to serial rescore).
template <int P>
__global__ __launch_bounds__(256) void knn_rescore4_kernel(
    const float* __restrict__ x, const float* __restrict__ x2,
    const int* __restrict__ pi,
    int* __restrict__ src, int* __restrict__ dst) {
#pragma clang fp contract(off)
  constexpr int CAND = P * TK;
  constexpr int LPT  = CAND / 4;
  __shared__ uint2 ls[4][16][64];   // [sub][slot][row-lane] = 32 KB

  const int tid  = threadIdx.x;
  const int lane = tid & 63;
  const int sub  = tid >> 6;
  const int r    = blockIdx.x * 64 + lane;
  const int b    = r >> 13;
  const int j    = r & (MM - 1);
  const float* __restrict__ xb = x + (size_t)b * MM * DD;
  const float x2j = x2[r];

  const float4* qp = (const float4*)(xb + (size_t)j * DD);
  float4 q0 = qp[0],  q1 = qp[1],  q2 = qp[2],  q3 = qp[3];
  float4 q4 = qp[4],  q5 = qp[5],  q6 = qp[6],  q7 = qp[7];
  float4 q8 = qp[8],  q9 = qp[9],  q10 = qp[10], q11 = qp[11];
  float4 q12 = qp[12], q13 = qp[13], q14 = qp[14], q15 = qp[15];

  const float INF = __builtin_inff();
  float e0 = INF, e1 = INF, e2 = INF, e3 = INF, e4 = INF, e5 = INF,
        e6 = INF, e7 = INF, e8 = INF, e9 = INF, e10 = INF, e11 = INF,
        e12 = INF, e13 = INF, e14 = INF, e15 = INF;
  int n0 = 0x7fffffff, n1 = 0x7fffffff, n2 = 0x7fffffff, n3 = 0x7fffffff,
      n4 = 0x7fffffff, n5 = 0x7fffffff, n6 = 0x7fffffff, n7 = 0x7fffffff,
      n8 = 0x7fffffff, n9 = 0x7fffffff, n10 = 0x7fffffff, n11 = 0x7fffffff,
      n12 = 0x7fffffff, n13 = 0x7fffffff, n14 = 0x7fffffff, n15 = 0x7fffffff;

  size_t base = (size_t)r * CAND + (size_t)sub * LPT;

  for (int t = 0; t < LPT; ++t) {
    int c = pi[base + t];
    const float4* pp = (const float4*)(xb + (size_t)c * DD);
    // FROZEN numerics: einsum baseline-SSE reversed muladd chain.
    float v0 = 0.f, v1 = 0.f, v2 = 0.f, v3 = 0.f;
    {
      float4 w0 = pp[0], w1 = pp[1], w2 = pp[2], w3 = pp[3];
      EBLK(q0, q1, q2, q3, w0, w1, w2, w3);
    }
    {
      float4 w0 = pp[4], w1 = pp[5], w2 = pp[6], w3 = pp[7];
      EBLK(q4, q5, q6, q7, w0, w1, w2, w3);
    }
    {
      float4 w0 = pp[8], w1 = pp[9], w2 = pp[10], w3 = pp[11];
      EBLK(q8, q9, q10, q11, w0, w1, w2, w3);
    }
    {
      float4 w0 = pp[12], w1 = pp[13], w2 = pp[14], w3 = pp[15];
      EBLK(q12, q13, q14, q15, w0, w1, w2, w3);
    }
    float dotf = (v0 + v1) + (v2 + v3);
    float s  = x2j + x2[b * MM + c];
    float tm = 2.0f * dotf;
    float d2 = s - tm;

    bool lt = (d2 < e15) || (d2 == e15 && c < n15);
    e15 = lt ? d2 : e15;
    n15 = lt ? c : n15;
    LBSTEP(e14, n14, e15, n15); LBSTEP(e13, n13, e14, n14);
    LBSTEP(e12, n12, e13, n13); LBSTEP(e11, n11, e12, n12);
    LBSTEP(e10, n10, e11, n11); LBSTEP(e9,  n9,  e10, n10);
    LBSTEP(e8,  n8,  e9,  n9);  LBSTEP(e7,  n7,  e8,  n8);
    LBSTEP(e6,  n6,  e7,  n7);  LBSTEP(e5,  n5,  e6,  n6);
    LBSTEP(e4,  n4,  e5,  n5);  LBSTEP(e3,  n3,  e4,  n4);
    LBSTEP(e2,  n2,  e3,  n3);  LBSTEP(e1,  n1,  e2,  n2);
    LBSTEP(e0,  n0,  e1,  n1);
  }

#define MONO(F) ({ int k_ = __float_as_int(F); \
                   (unsigned)k_ ^ ((unsigned)(k_ >> 31) | 0x80000000u); })
  ls[sub][0][lane]  = make_uint2(MONO(e0),  (unsigned)n0);
  ls[sub][1][lane]  = make_uint2(MONO(e1),  (unsigned)n1);
  ls[sub][2][lane]  = make_uint2(MONO(e2),  (unsigned)n2);
  ls[sub][3][lane]  = make_uint2(MONO(e3),  (unsigned)n3);
  ls[sub][4][lane]  = make_uint2(MONO(e4),  (unsigned)n4);
  ls[sub][5][lane]  = make_uint2(MONO(e5),  (unsigned)n5);
  ls[sub][6][lane]  = make_uint2(MONO(e6),  (unsigned)n6);
  ls[sub][7][lane]  = make_uint2(MONO(e7),  (unsigned)n7);
  ls[sub][8][lane]  = make_uint2(MONO(e8),  (unsigned)n8);
  ls[sub][9][lane]  = make_uint2(MONO(e9),  (unsigned)n9);
  ls[sub][10][lane] = make_uint2(MONO(e10), (unsigned)n10);
  ls[sub][11][lane] = make_uint2(MONO(e11), (unsigned)n11);
  ls[sub][12][lane] = make_uint2(MONO(e12), (unsigned)n12);
  ls[sub][13][lane] = make_uint2(MONO(e13), (unsigned)n13);
  ls[sub][14][lane] = make_uint2(MONO(e14), (unsigned)n14);
  ls[sub][15][lane] = make_uint2(MONO(e15), (unsigned)n15);
#undef MONO
  __syncthreads();

  if (sub == 0) {
    uint2 c0v = ls[0][0][lane];
    uint2 c1v = ls[1][0][lane];
    uint2 c2v = ls[2][0][lane];
    uint2 c3v = ls[3][0][lane];
    int h0 = 1, h1 = 1, h2 = 1, h3 = 1;
    const uint2 SENT = make_uint2(0xFFFFFFFFu, 0x7FFFFFFFu);
#define LESS2(A, B) ((A).x < (B).x || ((A).x == (B).x && (A).y < (B).y))
    for (int out = 0; out < KK; ++out) {
      bool l01 = LESS2(c0v, c1v);
      uint2 m01 = l01 ? c0v : c1v;
      int  w01 = l01 ? 0 : 1;
      bool l23 = LESS2(c2v, c3v);
      uint2 m23 = l23 ? c2v : c3v;
      int  w23 = l23 ? 2 : 3;
      bool lf = LESS2(m01, m23);
      uint2 mv = lf ? m01 : m23;
      int  wf = lf ? w01 : w23;

      src[(size_t)r * KK + out] = b * MM + (int)mv.y;
      dst[(size_t)r * KK + out] = r;

      if (wf == 0) { c0v = (h0 < 16) ? ls[0][h0][lane] : SENT; ++h0; }
      else if (wf == 1) { c1v = (h1 < 16) ? ls[1][h1][lane] : SENT; ++h1; }
      else if (wf == 2) { c2v = (h2 < 16) ? ls[2][h2][lane] : SENT; ++h2; }
      else              { c3v = (h3 < 16) ? ls[3][h3][lane] : SENT; ++h3; }
    }
#undef LESS2
  }
}

template <int P>
static void launch_all(const float* x, int* out, void* d_ws, hipStream_t stream) {
  char* ws = (char*)d_ws;
  float* x2 = (float*)ws;
  int*   pi = (int*)(ws + (size_t)NROWS * sizeof(float));

  int* src = out;
  int* dst = out + (size_t)NROWS * KK;

  norms_np_kernel<<<NROWS / 256, 256, 0, stream>>>(x, x2);
  knn_partial_q1_kernel<P><<<(NROWS / 256) * P, 256, 0, stream>>>(x, x2, pi);
  knn_rescore4_kernel<P><<<NROWS / 64, 256, 0, stream>>>(x, x2, pi, src, dst);
}

extern "C" void kernel_launch(void* const* d_in, const int* in_sizes, int n_in,
                              void* d_out, int out_size, void* d_ws, size_t ws_size,
                              hipStream_t stream) {
  const float* x = (const float*)d_in[0];
  int* out = (int*)d_out;

  auto need = [](int P) {
    return (size_t)NROWS * sizeof(float) +
           (size_t)NROWS * P * TK * sizeof(int);
  };

  if (ws_size >= need(8)) {
    launch_all<8>(x, out, d_ws, stream);   // 4096 waves = 4/SIMD
  } else if (ws_size >= need(4)) {
    launch_all<4>(x, out, d_ws, stream);
  } else if (ws_size >= need(2)) {
    launch_all<2>(x, out, d_ws, stream);
  } else {
    launch_all<1>(x, out, d_ws, stream);
  }
}